// Round 8
// baseline (286.491 us; speedup 1.0000x reference)
//
#include <hip/hip_runtime.h>
#include <hip/hip_bf16.h>

typedef float f32x4 __attribute__((ext_vector_type(4)));
typedef short s16x8 __attribute__((ext_vector_type(8)));

#define NB 4
#define NT 2048
#define NH 16
#define DK 64
#define DM 1024
#define MTOT (NB * NT)   // 8192
#define NTOT (3 * DM)    // 3072

// log2(e) / sqrt(64)
#define QSCALE 0.18033688011112042f
#define RESCALE_THR 8.0f

__device__ __forceinline__ unsigned short f2bf(float f) {
  union { float f; unsigned u; } v; v.f = f;
  unsigned r = v.u + 0x7fff + ((v.u >> 16) & 1);
  return (unsigned short)(r >> 16);
}

__device__ __forceinline__ unsigned cvt_pk_bf16(float a, float b) {
  unsigned r;
  asm("v_cvt_pk_bf16_f32 %0, %1, %2" : "=v"(r) : "v"(a), "v"(b));
  return r;
}

__device__ __forceinline__ void async_copy16(void* lds, const void* g) {
  __builtin_amdgcn_global_load_lds(
      (const __attribute__((address_space(1))) unsigned int*)g,
      (__attribute__((address_space(3))) unsigned int*)lds, 16, 0, 0);
}

// ---------------- x -> bf16 ----------------
__global__ void cvt_x_kernel(const float* __restrict__ x,
                             unsigned short* __restrict__ xb) {
  int i = (blockIdx.x * 256 + threadIdx.x) * 4;
  float4 v = *reinterpret_cast<const float4*>(x + i);
  ushort4 o;
  o.x = f2bf(v.x); o.y = f2bf(v.y); o.z = f2bf(v.z); o.w = f2bf(v.w);
  *reinterpret_cast<ushort4*>(xb + i) = o;
}

// ---------------- W (1024,3072) f32 -> WT (3072,1024) bf16 ----------------
__global__ void transpose_w_kernel(const float* __restrict__ W,
                                   unsigned short* __restrict__ WT) {
  __shared__ float tile[64][65];
  const int n0 = blockIdx.x * 64;   // over 3072
  const int k0 = blockIdx.y * 64;   // over 1024
  const int t = threadIdx.x;        // 256
  const int col = t & 63;
  const int rw = t >> 6;
#pragma unroll
  for (int r = 0; r < 16; r++) {
    int row = r * 4 + rw;           // k offset
    tile[row][col] = W[(size_t)(k0 + row) * NTOT + n0 + col];
  }
  __syncthreads();
#pragma unroll
  for (int r = 0; r < 16; r++) {
    int row = r * 4 + rw;           // n offset
    WT[(size_t)(n0 + row) * DM + k0 + col] = f2bf(tile[col][row]);
  }
}

// ---------------- QKV GEMM: C = Xb @ W + b, scatter to Q/K/VT ----------------
__global__ __launch_bounds__(256) void qkv_gemm_kernel(
    const unsigned short* __restrict__ A, const unsigned short* __restrict__ BT,
    const float* __restrict__ bias, unsigned short* __restrict__ Q,
    unsigned short* __restrict__ Kd, unsigned short* __restrict__ VT) {
  __shared__ unsigned short As[128 * 32];
  __shared__ unsigned short Bs[128 * 32];
  const int tid = threadIdx.x;
  const int lane = tid & 63;
  const int wave = tid >> 6;
  const int wr = wave >> 1, wc = wave & 1;
  const int l15 = lane & 15, lh = lane >> 4;

  const int nTilesN = NTOT / 128;  // 24
  const int tm = (blockIdx.x / nTilesN) * 128;
  const int tn = (blockIdx.x % nTilesN) * 128;

  f32x4 acc[4][4] = {};

  for (int k0 = 0; k0 < DM; k0 += 32) {
#pragma unroll
    for (int i = 0; i < 2; i++) {
      int gidx = i * 256 + tid;            // 0..511 chunks of 8 bf16
      int row = gidx >> 2;
      int col = (gidx & 3) << 3;
      async_copy16(&As[(i * 256 + wave * 64) * 8],
                   &A[(size_t)(tm + row) * DM + k0 + col]);
      async_copy16(&Bs[(i * 256 + wave * 64) * 8],
                   &BT[(size_t)(tn + row) * DM + k0 + col]);
    }
    __syncthreads();
    s16x8 af[4], bf[4];
#pragma unroll
    for (int mi = 0; mi < 4; mi++)
      af[mi] = *(const s16x8*)&As[(wr * 64 + mi * 16 + l15) * 32 + lh * 8];
#pragma unroll
    for (int ni = 0; ni < 4; ni++)
      bf[ni] = *(const s16x8*)&Bs[(wc * 64 + ni * 16 + l15) * 32 + lh * 8];
#pragma unroll
    for (int mi = 0; mi < 4; mi++)
#pragma unroll
      for (int ni = 0; ni < 4; ni++)
        acc[mi][ni] = __builtin_amdgcn_mfma_f32_16x16x32_bf16(
            af[mi], bf[ni], acc[mi][ni], 0, 0, 0);
    __syncthreads();
  }

  // epilogue: bias + scatter
  const int part = tn >> 10;  // 0=Q 1=K 2=V (uniform per block)
#pragma unroll
  for (int ni = 0; ni < 4; ni++) {
    const int n = tn + wc * 64 + ni * 16 + l15;
    const float bv = bias[n];
    const int n1 = n & 1023;
    const int h = n1 >> 6, d = n1 & 63;
#pragma unroll
    for (int mi = 0; mi < 4; mi++) {
#pragma unroll
      for (int r = 0; r < 4; r++) {
        const int m = tm + wr * 64 + mi * 16 + lh * 4 + r;
        const int b = m >> 11, t = m & 2047;
        float v = acc[mi][ni][r] + bv;
        if (part == 0) {
          v *= QSCALE;
          Q[((size_t)(b * NH + h) * NT + t) * DK + d] = f2bf(v);
        } else if (part == 1) {
          Kd[((size_t)(b * NH + h) * NT + t) * DK + d] = f2bf(v);
        } else {
          VT[((size_t)(b * NH + h) * DK + d) * NT + t] = f2bf(v);
        }
      }
    }
  }
}

// ---------------- Flash attention v5 -----------------------------------------
// r7 skeleton minus Vs staging: PV B-fragments are 16B-contiguous in VT, so
// load them directly from global (L2-served; issued after QK^T so softmax
// hides the latency). LDS 48->32KB -> 4 blocks/CU resident (grid = 4/CU, no
// tail). XCD swizzle (T1): each XCD owns 8 consecutive bh -> per-XCD L2
// working set = 8*(K+V) = 4MB = L2 size; V re-reads become L2-local.
// Q,K: (BH,T,64) bf16 (Q pre-scaled); VT: (BH,64,T) bf16; out fp32 (B,T,H,64).
// K LDS swizzle: 16B chunk c of row stored at c ^ (row & 7), both sides.
__global__ __launch_bounds__(256) void attn_kernel(
    const unsigned short* __restrict__ Q, const unsigned short* __restrict__ K,
    const unsigned short* __restrict__ VT, float* __restrict__ out) {
  __shared__ unsigned short Ks[2][64 * 64];   // [buf][key][d]  2x8KB
  __shared__ unsigned short Ps[4][32 * 64];   // per-wave P     16KB

  const int tid = threadIdx.x, lane = tid & 63, wave = tid >> 6;
  const int l15 = lane & 15, lh = lane >> 4;
  // XCD swizzle: 1024 blocks, 8 XCDs -> XCD x gets orig ids [x*128, x*128+128)
  const int orig = ((blockIdx.x & 7) << 7) + (blockIdx.x >> 3);
  const int bh = orig >> 4;
  const int qt = orig & 15;
  const size_t base = (size_t)bh * NT * DK;
  const int qrow0 = qt * 128 + wave * 32;

  // Q fragments (MFMA B operand): Q[query=l15][d=lh*8..]
  s16x8 qf[2][2];
#pragma unroll
  for (int mi = 0; mi < 2; mi++)
#pragma unroll
    for (int kk = 0; kk < 2; kk++)
      qf[mi][kk] = *(const s16x8*)&Q[base + (size_t)(qrow0 + mi * 16 + l15) * DK +
                                     kk * 32 + lh * 8];

  float mrow[2] = {-1e30f, -1e30f}, msum[2] = {0.0f, 0.0f};
  f32x4 acc_o[2][4] = {};

  // prologue: stage K tile 0 into buf 0 (swizzled global source, linear dest)
#pragma unroll
  for (int i = 0; i < 2; i++) {
    int gidx = i * 256 + tid;
    int row = gidx >> 3, c = gidx & 7;
    async_copy16(&Ks[0][(i * 256 + wave * 64) * 8],
                 &K[base + (size_t)row * DK + ((c ^ (row & 7)) << 3)]);
  }
  __syncthreads();

  int cur = 0;
  for (int j = 0; j < NT; j += 64) {
    // prefetch next K tile into the other buffer
    if (j + 64 < NT) {
      const int nb = cur ^ 1;
      const int jn = j + 64;
#pragma unroll
      for (int i = 0; i < 2; i++) {
        int gidx = i * 256 + tid;
        int row = gidx >> 3, c = gidx & 7;
        async_copy16(&Ks[nb][(i * 256 + wave * 64) * 8],
                     &K[base + (size_t)(jn + row) * DK + ((c ^ (row & 7)) << 3)]);
      }
    }

    // S^T = K @ Q^T : st[ki][mi] rows=keys(ki*16+lh*4+r), cols=queries(mi*16+l15)
    f32x4 st[4][2] = {};
    __builtin_amdgcn_s_setprio(1);
#pragma unroll
    for (int ki = 0; ki < 4; ki++) {
      const int row = ki * 16 + l15;
      const unsigned short* kr = &Ks[cur][row * 64];
      s16x8 kf0 = *(const s16x8*)&kr[((lh ^ (row & 7)) << 3)];
      s16x8 kf1 = *(const s16x8*)&kr[(((4 + lh) ^ (row & 7)) << 3)];
#pragma unroll
      for (int mi = 0; mi < 2; mi++) {
        st[ki][mi] = __builtin_amdgcn_mfma_f32_16x16x32_bf16(kf0, qf[mi][0], st[ki][mi], 0, 0, 0);
        st[ki][mi] = __builtin_amdgcn_mfma_f32_16x16x32_bf16(kf1, qf[mi][1], st[ki][mi], 0, 0, 0);
      }
    }
    __builtin_amdgcn_s_setprio(0);

    // V fragments direct from global (16B contiguous along key in VT);
    // issued here so the softmax VALU below hides the L2 latency.
    s16x8 vfr[2][4];
#pragma unroll
    for (int kk = 0; kk < 2; kk++)
#pragma unroll
      for (int nd = 0; nd < 4; nd++)
        vfr[kk][nd] = *(const s16x8*)&VT[base + (size_t)(nd * 16 + l15) * NT +
                                         j + kk * 32 + lh * 8];

    // per-lane tile max (16 keys per query per lane) + 2 shfl
    float pmax[2];
#pragma unroll
    for (int mi = 0; mi < 2; mi++) {
      float m = st[0][mi][0];
#pragma unroll
      for (int ki = 0; ki < 4; ki++)
#pragma unroll
        for (int r = 0; r < 4; r++) m = fmaxf(m, st[ki][mi][r]);
      m = fmaxf(m, __shfl_xor(m, 16, 64));
      m = fmaxf(m, __shfl_xor(m, 32, 64));
      pmax[mi] = m;
    }

    // defer-max (T13): rescale only when the running max grew by > THR
    const int ok = (pmax[0] - mrow[0] <= RESCALE_THR) &&
                   (pmax[1] - mrow[1] <= RESCALE_THR);
    if (!__all(ok)) {
      float scale[2];
#pragma unroll
      for (int mi = 0; mi < 2; mi++) {
        float mn = fmaxf(mrow[mi], pmax[mi]);
        scale[mi] = exp2f(mrow[mi] - mn);
        mrow[mi] = mn;
        msum[mi] *= scale[mi];
      }
#pragma unroll
      for (int mi = 0; mi < 2; mi++)
#pragma unroll
        for (int r = 0; r < 4; r++) {
          const float sc2 = __shfl(scale[mi], (lane & 48) | (lh * 4 + r), 64);
#pragma unroll
          for (int nd = 0; nd < 4; nd++) acc_o[mi][nd][r] *= sc2;
        }
    }

    // p = exp2(s - m); per-lane partial sums; pack to bf16 pairs; write Ps
#pragma unroll
    for (int mi = 0; mi < 2; mi++) {
      const int row = mi * 16 + l15;
      float lsum = 0.0f;
#pragma unroll
      for (int ki = 0; ki < 4; ki++) {
        float p0 = exp2f(st[ki][mi][0] - mrow[mi]);
        float p1 = exp2f(st[ki][mi][1] - mrow[mi]);
        float p2 = exp2f(st[ki][mi][2] - mrow[mi]);
        float p3 = exp2f(st[ki][mi][3] - mrow[mi]);
        lsum += (p0 + p1) + (p2 + p3);
        uint2 pr;
        pr.x = cvt_pk_bf16(p0, p1);
        pr.y = cvt_pk_bf16(p2, p3);
        const int chunk = ki * 2 + (lh >> 1);
        *(uint2*)&Ps[wave][row * 64 + ((chunk ^ (row & 7)) << 3) + (lh & 1) * 4] = pr;
      }
      msum[mi] += lsum;
    }

    // PV: P(32x64) @ V(64x64), V fragments already in registers
#pragma unroll
    for (int kk = 0; kk < 2; kk++) {
      const int r0 = l15, r1 = 16 + l15;
      s16x8 pa0 = *(const s16x8*)&Ps[wave][r0 * 64 + (((kk * 4 + lh) ^ (r0 & 7)) << 3)];
      s16x8 pa1 = *(const s16x8*)&Ps[wave][r1 * 64 + (((kk * 4 + lh) ^ (r1 & 7)) << 3)];
      __builtin_amdgcn_s_setprio(1);
#pragma unroll
      for (int nd = 0; nd < 4; nd++) {
        acc_o[0][nd] = __builtin_amdgcn_mfma_f32_16x16x32_bf16(pa0, vfr[kk][nd], acc_o[0][nd], 0, 0, 0);
        acc_o[1][nd] = __builtin_amdgcn_mfma_f32_16x16x32_bf16(pa1, vfr[kk][nd], acc_o[1][nd], 0, 0, 0);
      }
      __builtin_amdgcn_s_setprio(0);
    }

    __syncthreads();
    cur ^= 1;
  }

  // epilogue: reduce per-lane sums, normalize, store
  const int b = bh >> 4, h = bh & 15;
  float rinv[2];
#pragma unroll
  for (int mi = 0; mi < 2; mi++) {
    float s = msum[mi];
    s += __shfl_xor(s, 16, 64);
    s += __shfl_xor(s, 32, 64);
    rinv[mi] = 1.0f / s;
  }
#pragma unroll
  for (int mi = 0; mi < 2; mi++)
#pragma unroll
    for (int r = 0; r < 4; r++) {
      const float rb = __shfl(rinv[mi], (lane & 48) | (lh * 4 + r), 64);
      const int t = qrow0 + mi * 16 + lh * 4 + r;
#pragma unroll
      for (int nd = 0; nd < 4; nd++) {
        const int d = nd * 16 + l15;
        out[(((size_t)b * NT + t) * NH + h) * DK + d] = acc_o[mi][nd][r] * rb;
      }
    }
}

extern "C" void kernel_launch(void* const* d_in, const int* in_sizes, int n_in,
                              void* d_out, int out_size, void* d_ws, size_t ws_size,
                              hipStream_t stream) {
  const float* x = (const float*)d_in[0];
  const float* W = (const float*)d_in[1];
  const float* bias = (const float*)d_in[2];
  float* out = (float*)d_out;
  char* ws = (char*)d_ws;

  unsigned short* Xb = (unsigned short*)(ws);                       // 16.78 MB
  unsigned short* WT = (unsigned short*)(ws + 16777216);            // 6.29 MB
  unsigned short* Q  = (unsigned short*)(ws + 23068672);            // 16.78 MB
  unsigned short* Kd = (unsigned short*)(ws + 39845888);            // 16.78 MB
  unsigned short* VT = (unsigned short*)(ws + 56623104);            // 16.78 MB

  cvt_x_kernel<<<8192, 256, 0, stream>>>(x, Xb);
  transpose_w_kernel<<<dim3(48, 16), 256, 0, stream>>>(W, WT);
  qkv_gemm_kernel<<<1536, 256, 0, stream>>>(Xb, WT, bias, Q, Kd, VT);
  attn_kernel<<<1024, 256, 0, stream>>>(Q, Kd, VT, out);
}

// Round 9
// 235.730 us; speedup vs baseline: 1.2153x; 1.2153x over previous
//
#include <hip/hip_runtime.h>
#include <hip/hip_bf16.h>

typedef float f32x4 __attribute__((ext_vector_type(4)));
typedef short s16x8 __attribute__((ext_vector_type(8)));

#define NB 4
#define NT 2048
#define NH 16
#define DK 64
#define DM 1024
#define MTOT (NB * NT)   // 8192
#define NTOT (3 * DM)    // 3072

// log2(e) / sqrt(64)
#define QSCALE 0.18033688011112042f
#define RESCALE_THR 8.0f

__device__ __forceinline__ unsigned short f2bf(float f) {
  union { float f; unsigned u; } v; v.f = f;
  unsigned r = v.u + 0x7fff + ((v.u >> 16) & 1);
  return (unsigned short)(r >> 16);
}

__device__ __forceinline__ unsigned cvt_pk_bf16(float a, float b) {
  unsigned r;
  asm("v_cvt_pk_bf16_f32 %0, %1, %2" : "=v"(r) : "v"(a), "v"(b));
  return r;
}

__device__ __forceinline__ void async_copy16(void* lds, const void* g) {
  __builtin_amdgcn_global_load_lds(
      (const __attribute__((address_space(1))) unsigned int*)g,
      (__attribute__((address_space(3))) unsigned int*)lds, 16, 0, 0);
}

// ---------------- x -> bf16 ----------------
__global__ void cvt_x_kernel(const float* __restrict__ x,
                             unsigned short* __restrict__ xb) {
  int i = (blockIdx.x * 256 + threadIdx.x) * 4;
  float4 v = *reinterpret_cast<const float4*>(x + i);
  ushort4 o;
  o.x = f2bf(v.x); o.y = f2bf(v.y); o.z = f2bf(v.z); o.w = f2bf(v.w);
  *reinterpret_cast<ushort4*>(xb + i) = o;
}

// ---------------- W (1024,3072) f32 -> WT (3072,1024) bf16 ----------------
__global__ void transpose_w_kernel(const float* __restrict__ W,
                                   unsigned short* __restrict__ WT) {
  __shared__ float tile[64][65];
  const int n0 = blockIdx.x * 64;   // over 3072
  const int k0 = blockIdx.y * 64;   // over 1024
  const int t = threadIdx.x;        // 256
  const int col = t & 63;
  const int rw = t >> 6;
#pragma unroll
  for (int r = 0; r < 16; r++) {
    int row = r * 4 + rw;           // k offset
    tile[row][col] = W[(size_t)(k0 + row) * NTOT + n0 + col];
  }
  __syncthreads();
#pragma unroll
  for (int r = 0; r < 16; r++) {
    int row = r * 4 + rw;           // n offset
    WT[(size_t)(n0 + row) * DM + k0 + col] = f2bf(tile[col][row]);
  }
}

// ---------------- QKV GEMM: C = Xb @ W + b, scatter to Q/K/VT ----------------
__global__ __launch_bounds__(256) void qkv_gemm_kernel(
    const unsigned short* __restrict__ A, const unsigned short* __restrict__ BT,
    const float* __restrict__ bias, unsigned short* __restrict__ Q,
    unsigned short* __restrict__ Kd, unsigned short* __restrict__ VT) {
  __shared__ unsigned short As[128 * 32];
  __shared__ unsigned short Bs[128 * 32];
  const int tid = threadIdx.x;
  const int lane = tid & 63;
  const int wave = tid >> 6;
  const int wr = wave >> 1, wc = wave & 1;
  const int l15 = lane & 15, lh = lane >> 4;

  const int nTilesN = NTOT / 128;  // 24
  const int tm = (blockIdx.x / nTilesN) * 128;
  const int tn = (blockIdx.x % nTilesN) * 128;

  f32x4 acc[4][4] = {};

  for (int k0 = 0; k0 < DM; k0 += 32) {
#pragma unroll
    for (int i = 0; i < 2; i++) {
      int gidx = i * 256 + tid;            // 0..511 chunks of 8 bf16
      int row = gidx >> 2;
      int col = (gidx & 3) << 3;
      async_copy16(&As[(i * 256 + wave * 64) * 8],
                   &A[(size_t)(tm + row) * DM + k0 + col]);
      async_copy16(&Bs[(i * 256 + wave * 64) * 8],
                   &BT[(size_t)(tn + row) * DM + k0 + col]);
    }
    __syncthreads();
    s16x8 af[4], bf[4];
#pragma unroll
    for (int mi = 0; mi < 4; mi++)
      af[mi] = *(const s16x8*)&As[(wr * 64 + mi * 16 + l15) * 32 + lh * 8];
#pragma unroll
    for (int ni = 0; ni < 4; ni++)
      bf[ni] = *(const s16x8*)&Bs[(wc * 64 + ni * 16 + l15) * 32 + lh * 8];
#pragma unroll
    for (int mi = 0; mi < 4; mi++)
#pragma unroll
      for (int ni = 0; ni < 4; ni++)
        acc[mi][ni] = __builtin_amdgcn_mfma_f32_16x16x32_bf16(
            af[mi], bf[ni], acc[mi][ni], 0, 0, 0);
    __syncthreads();
  }

  // epilogue: bias + scatter
  const int part = tn >> 10;  // 0=Q 1=K 2=V (uniform per block)
#pragma unroll
  for (int ni = 0; ni < 4; ni++) {
    const int n = tn + wc * 64 + ni * 16 + l15;
    const float bv = bias[n];
    const int n1 = n & 1023;
    const int h = n1 >> 6, d = n1 & 63;
#pragma unroll
    for (int mi = 0; mi < 4; mi++) {
#pragma unroll
      for (int r = 0; r < 4; r++) {
        const int m = tm + wr * 64 + mi * 16 + lh * 4 + r;
        const int b = m >> 11, t = m & 2047;
        float v = acc[mi][ni][r] + bv;
        if (part == 0) {
          v *= QSCALE;
          Q[((size_t)(b * NH + h) * NT + t) * DK + d] = f2bf(v);
        } else if (part == 1) {
          Kd[((size_t)(b * NH + h) * NT + t) * DK + d] = f2bf(v);
        } else {
          VT[((size_t)(b * NH + h) * DK + d) * NT + t] = f2bf(v);
        }
      }
    }
  }
}

// ---------------- Flash attention v6 -----------------------------------------
// r7 skeleton at 32KB LDS so all 4 work-blocks/CU are resident (50% occ cap):
//  - Ks double-buffered (16KB), prefetch j+1 at tile start (global_load_lds)
//  - Vs SINGLE-buffered (8KB): loaded at tile start for the CURRENT tile,
//    ready at the mid-tile barrier (window = QK^T + softmax, L2-resident src)
//  - Ps halved to [32][32] per wave (8KB): PV in two kk-halves reusing the
//    same buffer (per-wave DS ops are in-order -> safe)
//  - XCD swizzle (T1, proven: FETCH 139->24.6MB), defer-max (T13),
//    per-lane partial sums, setprio (T5)
// Q,K: (BH,T,64) bf16 (Q pre-scaled); VT: (BH,64,T) bf16; out fp32 (B,T,H,64).
// K/V LDS swizzle: 16B chunk c of row stored at c ^ (row&7) (pre-swizzled
// global source, linear LDS dest). Ps swizzle: chunk c at c ^ ((row>>1)&3).
__global__ __launch_bounds__(256) void attn_kernel(
    const unsigned short* __restrict__ Q, const unsigned short* __restrict__ K,
    const unsigned short* __restrict__ VT, float* __restrict__ out) {
  __shared__ unsigned short Ks[2][64 * 64];   // [buf][key][d]  2x8KB
  __shared__ unsigned short Vs[64 * 64];      // [d][key]       8KB
  __shared__ unsigned short Ps[4][32 * 32];   // per-wave P half 8KB

  const int tid = threadIdx.x, lane = tid & 63, wave = tid >> 6;
  const int l15 = lane & 15, lh = lane >> 4;
  // XCD swizzle: 1024 blocks, 8 XCDs -> XCD x gets orig ids [x*128, x*128+128)
  const int orig = ((blockIdx.x & 7) << 7) + (blockIdx.x >> 3);
  const int bh = orig >> 4;
  const int qt = orig & 15;
  const size_t base = (size_t)bh * NT * DK;
  const int qrow0 = qt * 128 + wave * 32;

  // Q fragments (MFMA B operand): Q[query=l15][d=lh*8..]
  s16x8 qf[2][2];
#pragma unroll
  for (int mi = 0; mi < 2; mi++)
#pragma unroll
    for (int kk = 0; kk < 2; kk++)
      qf[mi][kk] = *(const s16x8*)&Q[base + (size_t)(qrow0 + mi * 16 + l15) * DK +
                                     kk * 32 + lh * 8];

  float mrow[2] = {-1e30f, -1e30f}, msum[2] = {0.0f, 0.0f};
  f32x4 acc_o[2][4] = {};

  // prologue: stage K tile 0 into buf 0 (swizzled global source, linear dest)
#pragma unroll
  for (int i = 0; i < 2; i++) {
    int gidx = i * 256 + tid;
    int row = gidx >> 3, c = gidx & 7;
    async_copy16(&Ks[0][(i * 256 + wave * 64) * 8],
                 &K[base + (size_t)row * DK + ((c ^ (row & 7)) << 3)]);
  }
  __syncthreads();

  int cur = 0;
  for (int j = 0; j < NT; j += 64) {
    // stage CURRENT V tile (ready at mid-tile barrier) + prefetch next K tile
#pragma unroll
    for (int i = 0; i < 2; i++) {
      int gidx = i * 256 + tid;
      int row = gidx >> 3, c = gidx & 7;
      async_copy16(&Vs[(i * 256 + wave * 64) * 8],
                   &VT[base + (size_t)row * NT + j + ((c ^ (row & 7)) << 3)]);
    }
    if (j + 64 < NT) {
      const int nb = cur ^ 1;
      const int jn = j + 64;
#pragma unroll
      for (int i = 0; i < 2; i++) {
        int gidx = i * 256 + tid;
        int row = gidx >> 3, c = gidx & 7;
        async_copy16(&Ks[nb][(i * 256 + wave * 64) * 8],
                     &K[base + (size_t)(jn + row) * DK + ((c ^ (row & 7)) << 3)]);
      }
    }

    // S^T = K @ Q^T : st[ki][mi] rows=keys(ki*16+lh*4+r), cols=queries(mi*16+l15)
    f32x4 st[4][2] = {};
    __builtin_amdgcn_s_setprio(1);
#pragma unroll
    for (int ki = 0; ki < 4; ki++) {
      const int row = ki * 16 + l15;
      const unsigned short* kr = &Ks[cur][row * 64];
      s16x8 kf0 = *(const s16x8*)&kr[((lh ^ (row & 7)) << 3)];
      s16x8 kf1 = *(const s16x8*)&kr[(((4 + lh) ^ (row & 7)) << 3)];
#pragma unroll
      for (int mi = 0; mi < 2; mi++) {
        st[ki][mi] = __builtin_amdgcn_mfma_f32_16x16x32_bf16(kf0, qf[mi][0], st[ki][mi], 0, 0, 0);
        st[ki][mi] = __builtin_amdgcn_mfma_f32_16x16x32_bf16(kf1, qf[mi][1], st[ki][mi], 0, 0, 0);
      }
    }
    __builtin_amdgcn_s_setprio(0);

    // per-lane tile max (16 keys per query per lane) + 2 shfl
    float pmax[2];
#pragma unroll
    for (int mi = 0; mi < 2; mi++) {
      float m = st[0][mi][0];
#pragma unroll
      for (int ki = 0; ki < 4; ki++)
#pragma unroll
        for (int r = 0; r < 4; r++) m = fmaxf(m, st[ki][mi][r]);
      m = fmaxf(m, __shfl_xor(m, 16, 64));
      m = fmaxf(m, __shfl_xor(m, 32, 64));
      pmax[mi] = m;
    }

    // defer-max (T13): rescale only when the running max grew by > THR
    const int ok = (pmax[0] - mrow[0] <= RESCALE_THR) &&
                   (pmax[1] - mrow[1] <= RESCALE_THR);
    if (!__all(ok)) {
      float scale[2];
#pragma unroll
      for (int mi = 0; mi < 2; mi++) {
        float mn = fmaxf(mrow[mi], pmax[mi]);
        scale[mi] = exp2f(mrow[mi] - mn);
        mrow[mi] = mn;
        msum[mi] *= scale[mi];
      }
#pragma unroll
      for (int mi = 0; mi < 2; mi++)
#pragma unroll
        for (int r = 0; r < 4; r++) {
          const float sc2 = __shfl(scale[mi], (lane & 48) | (lh * 4 + r), 64);
#pragma unroll
          for (int nd = 0; nd < 4; nd++) acc_o[mi][nd][r] *= sc2;
        }
    }

    // p = exp2(s - m); per-lane partial sums; pack into registers
    uint2 pw[2][4];   // [mi][ki]
#pragma unroll
    for (int mi = 0; mi < 2; mi++) {
      float lsum = 0.0f;
#pragma unroll
      for (int ki = 0; ki < 4; ki++) {
        float p0 = exp2f(st[ki][mi][0] - mrow[mi]);
        float p1 = exp2f(st[ki][mi][1] - mrow[mi]);
        float p2 = exp2f(st[ki][mi][2] - mrow[mi]);
        float p3 = exp2f(st[ki][mi][3] - mrow[mi]);
        lsum += (p0 + p1) + (p2 + p3);
        pw[mi][ki].x = cvt_pk_bf16(p0, p1);
        pw[mi][ki].y = cvt_pk_bf16(p2, p3);
      }
      msum[mi] += lsum;
    }

    __syncthreads();   // Vs (current tile) staged; Ks[nb] also drained

    // PV: P(32x64) @ V(64x64) in two kk-halves through the 2KB/wave Ps buffer
#pragma unroll
    for (int kk = 0; kk < 2; kk++) {
      // write this half's P (keys kk*32 .. kk*32+31)
#pragma unroll
      for (int mi = 0; mi < 2; mi++) {
        const int row = mi * 16 + l15;
#pragma unroll
        for (int k2 = 0; k2 < 2; k2++) {
          const int cw = k2 * 2 + (lh >> 1);
          *(uint2*)&Ps[wave][row * 32 + ((cw ^ ((row >> 1) & 3)) << 3) +
                             (lh & 1) * 4] = pw[mi][kk * 2 + k2];
        }
      }
      const int r0 = l15, r1 = 16 + l15;
      s16x8 pa0 = *(const s16x8*)&Ps[wave][r0 * 32 + (((lh ^ ((r0 >> 1) & 3))) << 3)];
      s16x8 pa1 = *(const s16x8*)&Ps[wave][r1 * 32 + (((lh ^ ((r1 >> 1) & 3))) << 3)];
      __builtin_amdgcn_s_setprio(1);
#pragma unroll
      for (int nd = 0; nd < 4; nd++) {
        const int vrow = nd * 16 + l15;
        s16x8 vf = *(const s16x8*)&Vs[vrow * 64 + (((kk * 4 + lh) ^ (vrow & 7)) << 3)];
        acc_o[0][nd] = __builtin_amdgcn_mfma_f32_16x16x32_bf16(pa0, vf, acc_o[0][nd], 0, 0, 0);
        acc_o[1][nd] = __builtin_amdgcn_mfma_f32_16x16x32_bf16(pa1, vf, acc_o[1][nd], 0, 0, 0);
      }
      __builtin_amdgcn_s_setprio(0);
    }

    __syncthreads();   // protect Vs (next tile's staging) and Ks buffers
    cur ^= 1;
  }

  // epilogue: reduce per-lane sums, normalize, store
  const int b = bh >> 4, h = bh & 15;
  float rinv[2];
#pragma unroll
  for (int mi = 0; mi < 2; mi++) {
    float s = msum[mi];
    s += __shfl_xor(s, 16, 64);
    s += __shfl_xor(s, 32, 64);
    rinv[mi] = 1.0f / s;
  }
#pragma unroll
  for (int mi = 0; mi < 2; mi++)
#pragma unroll
    for (int r = 0; r < 4; r++) {
      const float rb = __shfl(rinv[mi], (lane & 48) | (lh * 4 + r), 64);
      const int t = qrow0 + mi * 16 + lh * 4 + r;
#pragma unroll
      for (int nd = 0; nd < 4; nd++) {
        const int d = nd * 16 + l15;
        out[(((size_t)b * NT + t) * NH + h) * DK + d] = acc_o[mi][nd][r] * rb;
      }
    }
}

extern "C" void kernel_launch(void* const* d_in, const int* in_sizes, int n_in,
                              void* d_out, int out_size, void* d_ws, size_t ws_size,
                              hipStream_t stream) {
  const float* x = (const float*)d_in[0];
  const float* W = (const float*)d_in[1];
  const float* bias = (const float*)d_in[2];
  float* out = (float*)d_out;
  char* ws = (char*)d_ws;

  unsigned short* Xb = (unsigned short*)(ws);                       // 16.78 MB
  unsigned short* WT = (unsigned short*)(ws + 16777216);            // 6.29 MB
  unsigned short* Q  = (unsigned short*)(ws + 23068672);            // 16.78 MB
  unsigned short* Kd = (unsigned short*)(ws + 39845888);            // 16.78 MB
  unsigned short* VT = (unsigned short*)(ws + 56623104);            // 16.78 MB

  cvt_x_kernel<<<8192, 256, 0, stream>>>(x, Xb);
  transpose_w_kernel<<<dim3(48, 16), 256, 0, stream>>>(W, WT);
  qkv_gemm_kernel<<<1536, 256, 0, stream>>>(Xb, WT, bias, Q, Kd, VT);
  attn_kernel<<<1024, 256, 0, stream>>>(Q, Kd, VT, out);
}

// Round 10
// 216.676 us; speedup vs baseline: 1.3222x; 1.0879x over previous
//
#include <hip/hip_runtime.h>
#include <hip/hip_bf16.h>

typedef float f32x4 __attribute__((ext_vector_type(4)));
typedef short s16x8 __attribute__((ext_vector_type(8)));

#define NB 4
#define NT 2048
#define NH 16
#define DK 64
#define DM 1024
#define MTOT (NB * NT)   // 8192
#define NTOT (3 * DM)    // 3072

// log2(e) / sqrt(64)
#define QSCALE 0.18033688011112042f
#define RESCALE_THR 8.0f

__device__ __forceinline__ unsigned short f2bf(float f) {
  union { float f; unsigned u; } v; v.f = f;
  unsigned r = v.u + 0x7fff + ((v.u >> 16) & 1);
  return (unsigned short)(r >> 16);
}

__device__ __forceinline__ unsigned cvt_pk_bf16(float a, float b) {
  unsigned r;
  asm("v_cvt_pk_bf16_f32 %0, %1, %2" : "=v"(r) : "v"(a), "v"(b));
  return r;
}

__device__ __forceinline__ void async_copy16(void* lds, const void* g) {
  __builtin_amdgcn_global_load_lds(
      (const __attribute__((address_space(1))) unsigned int*)g,
      (__attribute__((address_space(3))) unsigned int*)lds, 16, 0, 0);
}

// ---------------- x -> bf16 ----------------
__global__ void cvt_x_kernel(const float* __restrict__ x,
                             unsigned short* __restrict__ xb) {
  int i = (blockIdx.x * 256 + threadIdx.x) * 4;
  float4 v = *reinterpret_cast<const float4*>(x + i);
  ushort4 o;
  o.x = f2bf(v.x); o.y = f2bf(v.y); o.z = f2bf(v.z); o.w = f2bf(v.w);
  *reinterpret_cast<ushort4*>(xb + i) = o;
}

// ---------------- W (1024,3072) f32 -> WT (3072,1024) bf16 ----------------
__global__ void transpose_w_kernel(const float* __restrict__ W,
                                   unsigned short* __restrict__ WT) {
  __shared__ float tile[64][65];
  const int n0 = blockIdx.x * 64;   // over 3072
  const int k0 = blockIdx.y * 64;   // over 1024
  const int t = threadIdx.x;        // 256
  const int col = t & 63;
  const int rw = t >> 6;
#pragma unroll
  for (int r = 0; r < 16; r++) {
    int row = r * 4 + rw;           // k offset
    tile[row][col] = W[(size_t)(k0 + row) * NTOT + n0 + col];
  }
  __syncthreads();
#pragma unroll
  for (int r = 0; r < 16; r++) {
    int row = r * 4 + rw;           // n offset
    WT[(size_t)(n0 + row) * DM + k0 + col] = f2bf(tile[col][row]);
  }
}

// ---------------- QKV GEMM: C = Xb @ W + b, scatter to Q/K/VT ----------------
__global__ __launch_bounds__(256) void qkv_gemm_kernel(
    const unsigned short* __restrict__ A, const unsigned short* __restrict__ BT,
    const float* __restrict__ bias, unsigned short* __restrict__ Q,
    unsigned short* __restrict__ Kd, unsigned short* __restrict__ VT) {
  __shared__ unsigned short As[128 * 32];
  __shared__ unsigned short Bs[128 * 32];
  const int tid = threadIdx.x;
  const int lane = tid & 63;
  const int wave = tid >> 6;
  const int wr = wave >> 1, wc = wave & 1;
  const int l15 = lane & 15, lh = lane >> 4;

  const int nTilesN = NTOT / 128;  // 24
  const int tm = (blockIdx.x / nTilesN) * 128;
  const int tn = (blockIdx.x % nTilesN) * 128;

  f32x4 acc[4][4] = {};

  for (int k0 = 0; k0 < DM; k0 += 32) {
#pragma unroll
    for (int i = 0; i < 2; i++) {
      int gidx = i * 256 + tid;            // 0..511 chunks of 8 bf16
      int row = gidx >> 2;
      int col = (gidx & 3) << 3;
      async_copy16(&As[(i * 256 + wave * 64) * 8],
                   &A[(size_t)(tm + row) * DM + k0 + col]);
      async_copy16(&Bs[(i * 256 + wave * 64) * 8],
                   &BT[(size_t)(tn + row) * DM + k0 + col]);
    }
    __syncthreads();
    s16x8 af[4], bf[4];
#pragma unroll
    for (int mi = 0; mi < 4; mi++)
      af[mi] = *(const s16x8*)&As[(wr * 64 + mi * 16 + l15) * 32 + lh * 8];
#pragma unroll
    for (int ni = 0; ni < 4; ni++)
      bf[ni] = *(const s16x8*)&Bs[(wc * 64 + ni * 16 + l15) * 32 + lh * 8];
#pragma unroll
    for (int mi = 0; mi < 4; mi++)
#pragma unroll
      for (int ni = 0; ni < 4; ni++)
        acc[mi][ni] = __builtin_amdgcn_mfma_f32_16x16x32_bf16(
            af[mi], bf[ni], acc[mi][ni], 0, 0, 0);
    __syncthreads();
  }

  // epilogue: bias + scatter
  const int part = tn >> 10;  // 0=Q 1=K 2=V (uniform per block)
#pragma unroll
  for (int ni = 0; ni < 4; ni++) {
    const int n = tn + wc * 64 + ni * 16 + l15;
    const float bv = bias[n];
    const int n1 = n & 1023;
    const int h = n1 >> 6, d = n1 & 63;
#pragma unroll
    for (int mi = 0; mi < 4; mi++) {
#pragma unroll
      for (int r = 0; r < 4; r++) {
        const int m = tm + wr * 64 + mi * 16 + lh * 4 + r;
        const int b = m >> 11, t = m & 2047;
        float v = acc[mi][ni][r] + bv;
        if (part == 0) {
          v *= QSCALE;
          Q[((size_t)(b * NH + h) * NT + t) * DK + d] = f2bf(v);
        } else if (part == 1) {
          Kd[((size_t)(b * NH + h) * NT + t) * DK + d] = f2bf(v);
        } else {
          VT[((size_t)(b * NH + h) * DK + d) * NT + t] = f2bf(v);
        }
      }
    }
  }
}

// ---------------- Flash attention v7 (8-wave blocks) -------------------------
// r9 structure, but 512-thread / 8-wave blocks (HK attn shape): grid 512 =
// 2 blocks/CU; if residency is ~2 blocks regardless of size (r7-r9 evidence:
// occupancy pinned ~21% across 32-48KB LDS), this doubles waves/CU to ~16 and
// halves per-wave staging + barrier cost (8 waves amortize one K/V staging).
//  - Ks double-buffered (16KB, global_load_lds, prefetch j+1 at tile start)
//  - Vs single-buffered (8KB), staged at tile start, ready at mid barrier
//  - Ps [8][32*32] (16KB), PV in two kk-halves through 2KB/wave
//  - XCD swizzle (T1), defer-max (T13), per-lane partial sums, setprio (T5)
// Q,K: (BH,T,64) bf16 (Q pre-scaled); VT: (BH,64,T) bf16; out fp32 (B,T,H,64).
// K/V swizzle: 16B chunk c of row at c^(row&7) (pre-swizzled global source,
// linear LDS dest). Ps swizzle: chunk c at c^((row>>1)&3).
__global__ __launch_bounds__(512) void attn_kernel(
    const unsigned short* __restrict__ Q, const unsigned short* __restrict__ K,
    const unsigned short* __restrict__ VT, float* __restrict__ out) {
  __shared__ unsigned short Ks[2][64 * 64];   // [buf][key][d]  2x8KB
  __shared__ unsigned short Vs[64 * 64];      // [d][key]       8KB
  __shared__ unsigned short Ps[8][32 * 32];   // per-wave P half 16KB

  const int tid = threadIdx.x, lane = tid & 63, wave = tid >> 6;
  const int l15 = lane & 15, lh = lane >> 4;
  // XCD swizzle: 512 blocks, 8 XCDs -> XCD x gets orig ids [x*64, x*64+64)
  const int orig = ((blockIdx.x & 7) << 6) + (blockIdx.x >> 3);
  const int bh = orig >> 3;         // 64 (b,h) pairs
  const int qt = orig & 7;          // 8 q-tiles of 256 rows
  const size_t base = (size_t)bh * NT * DK;
  const int qrow0 = qt * 256 + wave * 32;

  // staging geometry: 512 threads cover one 64x64 bf16 tile (1 chunk each)
  const int srow = tid >> 3, schunk = tid & 7;
  const int ssw = ((schunk ^ (srow & 7)) << 3);

  // Q fragments (MFMA B operand): Q[query=l15][d=lh*8..]
  s16x8 qf[2][2];
#pragma unroll
  for (int mi = 0; mi < 2; mi++)
#pragma unroll
    for (int kk = 0; kk < 2; kk++)
      qf[mi][kk] = *(const s16x8*)&Q[base + (size_t)(qrow0 + mi * 16 + l15) * DK +
                                     kk * 32 + lh * 8];

  float mrow[2] = {-1e30f, -1e30f}, msum[2] = {0.0f, 0.0f};
  f32x4 acc_o[2][4] = {};

  // prologue: stage K tile 0 into buf 0 (swizzled global source, linear dest)
  async_copy16(&Ks[0][(wave * 64) * 8], &K[base + (size_t)srow * DK + ssw]);
  __syncthreads();

  int cur = 0;
  for (int j = 0; j < NT; j += 64) {
    // stage CURRENT V tile (ready at mid barrier) + prefetch next K tile
    async_copy16(&Vs[(wave * 64) * 8], &VT[base + (size_t)srow * NT + j + ssw]);
    if (j + 64 < NT) {
      async_copy16(&Ks[cur ^ 1][(wave * 64) * 8],
                   &K[base + (size_t)(j + 64 + srow) * DK + ssw]);
    }

    // S^T = K @ Q^T : st[ki][mi] rows=keys(ki*16+lh*4+r), cols=queries(mi*16+l15)
    f32x4 st[4][2] = {};
    __builtin_amdgcn_s_setprio(1);
#pragma unroll
    for (int ki = 0; ki < 4; ki++) {
      const int row = ki * 16 + l15;
      const unsigned short* kr = &Ks[cur][row * 64];
      s16x8 kf0 = *(const s16x8*)&kr[((lh ^ (row & 7)) << 3)];
      s16x8 kf1 = *(const s16x8*)&kr[(((4 + lh) ^ (row & 7)) << 3)];
#pragma unroll
      for (int mi = 0; mi < 2; mi++) {
        st[ki][mi] = __builtin_amdgcn_mfma_f32_16x16x32_bf16(kf0, qf[mi][0], st[ki][mi], 0, 0, 0);
        st[ki][mi] = __builtin_amdgcn_mfma_f32_16x16x32_bf16(kf1, qf[mi][1], st[ki][mi], 0, 0, 0);
      }
    }
    __builtin_amdgcn_s_setprio(0);

    // per-lane tile max (16 keys per query per lane; max3-friendly) + 2 shfl
    float pmax[2];
#pragma unroll
    for (int mi = 0; mi < 2; mi++) {
      float m0 = fmaxf(fmaxf(st[0][mi][0], st[0][mi][1]),
                       fmaxf(st[0][mi][2], st[0][mi][3]));
#pragma unroll
      for (int ki = 1; ki < 4; ki++) {
        m0 = fmaxf(fmaxf(m0, st[ki][mi][0]), fmaxf(st[ki][mi][1], st[ki][mi][2]));
        m0 = fmaxf(m0, st[ki][mi][3]);
      }
      m0 = fmaxf(m0, __shfl_xor(m0, 16, 64));
      m0 = fmaxf(m0, __shfl_xor(m0, 32, 64));
      pmax[mi] = m0;
    }

    // defer-max (T13): rescale only when the running max grew by > THR
    const int ok = (pmax[0] - mrow[0] <= RESCALE_THR) &&
                   (pmax[1] - mrow[1] <= RESCALE_THR);
    if (!__all(ok)) {
      float scale[2];
#pragma unroll
      for (int mi = 0; mi < 2; mi++) {
        float mn = fmaxf(mrow[mi], pmax[mi]);
        scale[mi] = exp2f(mrow[mi] - mn);
        mrow[mi] = mn;
        msum[mi] *= scale[mi];
      }
#pragma unroll
      for (int mi = 0; mi < 2; mi++)
#pragma unroll
        for (int r = 0; r < 4; r++) {
          const float sc2 = __shfl(scale[mi], (lane & 48) | (lh * 4 + r), 64);
#pragma unroll
          for (int nd = 0; nd < 4; nd++) acc_o[mi][nd][r] *= sc2;
        }
    }

    // p = exp2(s - m); per-lane partial sums; pack into registers
    uint2 pw[2][4];   // [mi][ki]
#pragma unroll
    for (int mi = 0; mi < 2; mi++) {
      float lsum = 0.0f;
#pragma unroll
      for (int ki = 0; ki < 4; ki++) {
        float p0 = exp2f(st[ki][mi][0] - mrow[mi]);
        float p1 = exp2f(st[ki][mi][1] - mrow[mi]);
        float p2 = exp2f(st[ki][mi][2] - mrow[mi]);
        float p3 = exp2f(st[ki][mi][3] - mrow[mi]);
        lsum += (p0 + p1) + (p2 + p3);
        pw[mi][ki].x = cvt_pk_bf16(p0, p1);
        pw[mi][ki].y = cvt_pk_bf16(p2, p3);
      }
      msum[mi] += lsum;
    }

    __syncthreads();   // Vs (current tile) staged; Ks[cur^1] also drained

    // PV: P(32x64) @ V(64x64) in two kk-halves through the 2KB/wave Ps buffer
#pragma unroll
    for (int kk = 0; kk < 2; kk++) {
#pragma unroll
      for (int mi = 0; mi < 2; mi++) {
        const int row = mi * 16 + l15;
#pragma unroll
        for (int k2 = 0; k2 < 2; k2++) {
          const int cw = k2 * 2 + (lh >> 1);
          *(uint2*)&Ps[wave][row * 32 + ((cw ^ ((row >> 1) & 3)) << 3) +
                             (lh & 1) * 4] = pw[mi][kk * 2 + k2];
        }
      }
      const int r0 = l15, r1 = 16 + l15;
      s16x8 pa0 = *(const s16x8*)&Ps[wave][r0 * 32 + (((lh ^ ((r0 >> 1) & 3))) << 3)];
      s16x8 pa1 = *(const s16x8*)&Ps[wave][r1 * 32 + (((lh ^ ((r1 >> 1) & 3))) << 3)];
      __builtin_amdgcn_s_setprio(1);
#pragma unroll
      for (int nd = 0; nd < 4; nd++) {
        const int vrow = nd * 16 + l15;
        s16x8 vf = *(const s16x8*)&Vs[vrow * 64 + (((kk * 4 + lh) ^ (vrow & 7)) << 3)];
        acc_o[0][nd] = __builtin_amdgcn_mfma_f32_16x16x32_bf16(pa0, vf, acc_o[0][nd], 0, 0, 0);
        acc_o[1][nd] = __builtin_amdgcn_mfma_f32_16x16x32_bf16(pa1, vf, acc_o[1][nd], 0, 0, 0);
      }
      __builtin_amdgcn_s_setprio(0);
    }

    __syncthreads();   // protect Vs and Ks buffers before next tile's staging
    cur ^= 1;
  }

  // epilogue: reduce per-lane sums, normalize, store
  const int b = bh >> 4, h = bh & 15;
  float rinv[2];
#pragma unroll
  for (int mi = 0; mi < 2; mi++) {
    float s = msum[mi];
    s += __shfl_xor(s, 16, 64);
    s += __shfl_xor(s, 32, 64);
    rinv[mi] = 1.0f / s;
  }
#pragma unroll
  for (int mi = 0; mi < 2; mi++)
#pragma unroll
    for (int r = 0; r < 4; r++) {
      const float rb = __shfl(rinv[mi], (lane & 48) | (lh * 4 + r), 64);
      const int t = qrow0 + mi * 16 + lh * 4 + r;
#pragma unroll
      for (int nd = 0; nd < 4; nd++) {
        const int d = nd * 16 + l15;
        out[(((size_t)b * NT + t) * NH + h) * DK + d] = acc_o[mi][nd][r] * rb;
      }
    }
}

extern "C" void kernel_launch(void* const* d_in, const int* in_sizes, int n_in,
                              void* d_out, int out_size, void* d_ws, size_t ws_size,
                              hipStream_t stream) {
  const float* x = (const float*)d_in[0];
  const float* W = (const float*)d_in[1];
  const float* bias = (const float*)d_in[2];
  float* out = (float*)d_out;
  char* ws = (char*)d_ws;

  unsigned short* Xb = (unsigned short*)(ws);                       // 16.78 MB
  unsigned short* WT = (unsigned short*)(ws + 16777216);            // 6.29 MB
  unsigned short* Q  = (unsigned short*)(ws + 23068672);            // 16.78 MB
  unsigned short* Kd = (unsigned short*)(ws + 39845888);            // 16.78 MB
  unsigned short* VT = (unsigned short*)(ws + 56623104);            // 16.78 MB

  cvt_x_kernel<<<8192, 256, 0, stream>>>(x, Xb);
  transpose_w_kernel<<<dim3(48, 16), 256, 0, stream>>>(W, WT);
  qkv_gemm_kernel<<<1536, 256, 0, stream>>>(Xb, WT, bias, Q, Kd, VT);
  attn_kernel<<<512, 512, 0, stream>>>(Q, Kd, VT, out);
}